// Round 21
// baseline (141.832 us; speedup 1.0000x reference)
//
#include <hip/hip_runtime.h>

namespace {
constexpr int B_ = 64, S_ = 200, DV_ = 128, NC2_ = 4096;
}

typedef float f4v __attribute__((ext_vector_type(4)));
typedef float f32x4 __attribute__((ext_vector_type(4)));
typedef _Float16 half8 __attribute__((ext_vector_type(8)));

// LDS-only barrier: no vmcnt drain.
__device__ __forceinline__ void lds_sync() {
  asm volatile("s_waitcnt lgkmcnt(0)\n\ts_barrier" ::: "memory");
}

// ---------------------------------------------------------------------------
// K1: blocks [0,64):    GRU per batch (R17 loop) + swizzled f16 history +
//                       alpha s-tiles INTERLEAVED into the loop (1 tile per
//                       16 steps, rides latency stalls), per-wave partial
//                       strips (no atomics), final reduce.
//     blocks [64,192):  per-batch-half {parallel scan (redundant) ->
//                       100-row streaming fill}. 2 blocks per batch.
// ---------------------------------------------------------------------------
__global__ __launch_bounds__(512, 1) void k1_main(
    const int* __restrict__ c2_seq, const int* __restrict__ d_seq,
    const int* __restrict__ r_seq, const float* __restrict__ D_emb,
    const float* __restrict__ v_d, const float* __restrict__ v_c2,
    const float* __restrict__ R_emb,
    const float* __restrict__ W_ih, const float* __restrict__ W_hh,
    const float* __restrict__ b_ih, const float* __restrict__ b_hh,
    const float* __restrict__ W1, const float* __restrict__ b1,
    const float* __restrict__ W2, const float* __restrict__ b2,
    const float* __restrict__ W3, const float* __restrict__ b3,
    const float* __restrict__ W4, const float* __restrict__ b4,
    float* __restrict__ out_alpha, float* __restrict__ out_h,
    float* __restrict__ out_c2)
{
  __shared__ __align__(16) char smem[18944 + 208 * DV_ * 2 + 8 * 208 * 4];
  const int tid = threadIdx.x;

  if (blockIdx.x < B_) {
    // ------------------ GRU for batch b ------------------
    const int b = blockIdx.x;
    _Float16* hist = reinterpret_cast<_Float16*>(smem);          // [2][128] f16
    float* gl = reinterpret_cast<float*>(smem + 512);            // [200]
    int* rl = reinterpret_cast<int*>(smem + 1312);               // [200]
    float* u_l = reinterpret_cast<float*>(smem + 2112);          // [384] x4
    float* p0_l = u_l + 384;
    float* p1_l = p0_l + 384;
    float* bh_l = p1_l + 384;
    _Float16* fullh = reinterpret_cast<_Float16*>(smem + 18944); // [208][128]
    float* strips = reinterpret_cast<float*>(smem + 18944 + 208 * DV_ * 2); // [8][208]

    for (int i = tid; i < S_; i += 512) {
      gl[i] = D_emb[d_seq[b * S_ + i]];
      rl[i] = r_seq[b * S_ + i];
    }
    if (tid < 256) reinterpret_cast<_Float16*>(hist)[tid] = (_Float16)0.f;
    // zero fullh rows 200..207 (tail tile padding)
    {
      uint* fz = reinterpret_cast<uint*>(fullh + 200 * DV_);
      for (int i = tid; i < 8 * DV_ / 2; i += 512) fz[i] = 0u;
    }

    // collapsed input projections per gate row -> LDS
    if (tid < 384) {
      const int row = tid;
      const float4* wi =
          reinterpret_cast<const float4*>(W_ih + (size_t)row * 2 * DV_);
      const float4* vd4 = reinterpret_cast<const float4*>(v_d);
      const float4* re4 = reinterpret_cast<const float4*>(R_emb);
      float uu = 0.f, pp0 = 0.f, pp1 = 0.f;
#pragma unroll 8
      for (int k = 0; k < DV_ / 4; ++k) {
        float4 a = wi[k], vv = vd4[k];
        uu += a.x * vv.x + a.y * vv.y + a.z * vv.z + a.w * vv.w;
        float4 c = wi[DV_ / 4 + k];
        float4 r0 = re4[k], r1 = re4[DV_ / 4 + k];
        pp0 += c.x * r0.x + c.y * r0.y + c.z * r0.z + c.w * r0.w;
        pp1 += c.x * r1.x + c.y * r1.y + c.z * r1.z + c.w * r1.w;
      }
      const float bi = b_ih[row];
      u_l[row] = uu; p0_l[row] = pp0 + bi; p1_l[row] = pp1 + bi;
      bh_l[row] = b_hh[row];
    }

    // B-fragments (W_hh^T): lane l holds B[k=(l>>4)*8+j][col=l&15].
    const int w = tid >> 6, l = tid & 63;
    const int col = l & 15, kg = l >> 4;
    const int d = 16 * w + col;
    half8 bf[3][4];
#pragma unroll
    for (int g = 0; g < 3; ++g) {
      const float* wr = W_hh + (size_t)(g * DV_ + d) * DV_;
#pragma unroll
      for (int kt = 0; kt < 4; ++kt) {
        const int k0 = kt * 32 + kg * 8;
        const float4 lo = *reinterpret_cast<const float4*>(wr + k0);
        const float4 hi = *reinterpret_cast<const float4*>(wr + k0 + 4);
        half8 hb;
        hb[0] = (_Float16)lo.x; hb[1] = (_Float16)lo.y;
        hb[2] = (_Float16)lo.z; hb[3] = (_Float16)lo.w;
        hb[4] = (_Float16)hi.x; hb[5] = (_Float16)hi.y;
        hb[6] = (_Float16)hi.z; hb[7] = (_Float16)hi.w;
        bf[g][kt] = hb;
      }
    }
    // alpha B-fragments (W1^T) — held through the loop (16 VGPR)
    half8 bf1[4];
    {
      const float* wr1 = W1 + (size_t)d * DV_;
#pragma unroll
      for (int kt = 0; kt < 4; ++kt) {
        const int k0 = kt * 32 + kg * 8;
        const float4 lo = *reinterpret_cast<const float4*>(wr1 + k0);
        const float4 hi = *reinterpret_cast<const float4*>(wr1 + k0 + 4);
        half8 hb;
        hb[0] = (_Float16)lo.x; hb[1] = (_Float16)lo.y;
        hb[2] = (_Float16)lo.z; hb[3] = (_Float16)lo.w;
        hb[4] = (_Float16)hi.x; hb[5] = (_Float16)hi.y;
        hb[6] = (_Float16)hi.z; hb[7] = (_Float16)hi.w;
        bf1[kt] = hb;
      }
    }
    const float b1v = b1[d], w2v = W2[d];
    __syncthreads();

    float u3[3], p03[3], p13[3], bh3[3];
#pragma unroll
    for (int g = 0; g < 3; ++g) {
      u3[g] = u_l[g * DV_ + d];
      p03[g] = p0_l[g * DV_ + d];
      p13[g] = p1_l[g * DV_ + d];
      bh3[g] = bh_l[g * DV_ + d];
    }
    float hprev = 0.f;
    float gv = gl[0];
    int rv = rl[0];

    float* outp = out_h + (size_t)b * S_ * DV_ + d;
    for (int t = 0; t < S_; ++t) {
      // ---- interleaved alpha tile (rides the latency stalls) ----
      if ((t & 15) == 0 && t >= 16) {
        const int st = (t >> 4) - 1;          // 0..11
        const int row = 16 * st + col;
        half8 af2[4];
#pragma unroll
        for (int kt = 0; kt < 4; ++kt) {
          const int c0 = (kt * 32 + kg * 8) ^ ((row & 7) << 3);
          af2[kt] = *reinterpret_cast<const half8*>(&fullh[row * DV_ + c0]);
        }
        f32x4 y = {0.f, 0.f, 0.f, 0.f};
#pragma unroll
        for (int kt = 0; kt < 4; ++kt)
          y = __builtin_amdgcn_mfma_f32_16x16x32_f16(af2[kt], bf1[kt], y, 0, 0, 0);
#pragma unroll
        for (int j = 0; j < 4; ++j) {
          float part = w2v * fmaxf(y[j] + b1v, 0.f);
          part += __shfl_xor(part, 1);
          part += __shfl_xor(part, 2);
          part += __shfl_xor(part, 4);
          part += __shfl_xor(part, 8);
          if (col == 0) strips[w * 208 + 16 * st + 4 * kg + j] = part;
        }
      }
      // ---- GRU step ----
      const int cur = t & 1;
      half8 af[4];
#pragma unroll
      for (int kt = 0; kt < 4; ++kt)
        af[kt] = *reinterpret_cast<const half8*>(&hist[cur * DV_ + kt * 32 + kg * 8]);
      f32x4 a0 = {0.f, 0.f, 0.f, 0.f}, a1 = a0, a2 = a0;
#pragma unroll
      for (int kt = 0; kt < 4; ++kt) {
        a0 = __builtin_amdgcn_mfma_f32_16x16x32_f16(af[kt], bf[0][kt], a0, 0, 0, 0);
        a1 = __builtin_amdgcn_mfma_f32_16x16x32_f16(af[kt], bf[1][kt], a1, 0, 0, 0);
        a2 = __builtin_amdgcn_mfma_f32_16x16x32_f16(af[kt], bf[2][kt], a2, 0, 0, 0);
      }
      const float xr = gv * u3[0] + (rv ? p13[0] : p03[0]);
      const float xz = gv * u3[1] + (rv ? p13[1] : p03[1]);
      const float xn = gv * u3[2] + (rv ? p13[2] : p03[2]);
      const float r = 1.f / (1.f + __expf(-(xr + a0[0] + bh3[0])));
      const float z = 1.f / (1.f + __expf(-(xz + a1[0] + bh3[1])));
      const float nx = xn + r * (a2[0] + bh3[2]);
      const float e2 = __expf(2.f * nx);
      const float n = (e2 - 1.f) / (e2 + 1.f);
      const float hnew = (1.f - z) * n + z * hprev;
      hprev = hnew;
      if (kg == 0) {
        outp[(size_t)t * DV_] = hnew;                 // fire-and-forget f32
        const _Float16 hf = (_Float16)hnew;
        hist[(cur ^ 1) * DV_ + d] = hf;
        fullh[t * DV_ + (d ^ ((t & 7) << 3))] = hf;   // swizzled history
      }
      if (t + 1 < S_) { gv = gl[t + 1]; rv = rl[t + 1]; }
      lds_sync();
    }

    // ---- last alpha tile (st=12, rows 192..207; 200..207 are zero-pad) ----
    {
      const int st = 12;
      const int row = 16 * st + col;
      half8 af2[4];
#pragma unroll
      for (int kt = 0; kt < 4; ++kt) {
        const int c0 = (kt * 32 + kg * 8) ^ ((row & 7) << 3);
        af2[kt] = *reinterpret_cast<const half8*>(&fullh[row * DV_ + c0]);
      }
      f32x4 y = {0.f, 0.f, 0.f, 0.f};
#pragma unroll
      for (int kt = 0; kt < 4; ++kt)
        y = __builtin_amdgcn_mfma_f32_16x16x32_f16(af2[kt], bf1[kt], y, 0, 0, 0);
#pragma unroll
      for (int j = 0; j < 4; ++j) {
        float part = w2v * fmaxf(y[j] + b1v, 0.f);
        part += __shfl_xor(part, 1);
        part += __shfl_xor(part, 2);
        part += __shfl_xor(part, 4);
        part += __shfl_xor(part, 8);
        if (col == 0) strips[w * 208 + 16 * st + 4 * kg + j] = part;
      }
    }
    lds_sync();
    // ---- final alpha reduce across 8 wave-strips ----
    const float b2v = b2[0];
    for (int i = tid; i < S_; i += 512) {
      float s = b2v;
#pragma unroll
      for (int ww = 0; ww < 8; ++ww) s += strips[ww * 208 + i];
      out_alpha[b * S_ + i] = s;
    }
  } else {
    // ------- per-batch-half {redundant scan -> 100-row streaming fill} -----
    const int fb = blockIdx.x - B_;
    const int b = fb >> 1, half = fb & 1;
    const int s0 = half * 100;
    float* a3s = reinterpret_cast<float*>(smem);            // [128] x5
    float* u3s = a3s + DV_;
    float* q0s = u3s + DV_;
    float* q1s = q0s + DV_;
    float* w4s = q1s + DV_;
    float* vals = w4s + DV_;                                // [200]
    float* gl = vals + S_;                                  // [200]
    int* rl = reinterpret_cast<int*>(gl + S_);
    int* jl = rl + S_;
    int* prevs = jl + S_;
    int* done = prevs + S_;
    int* nresp = done + S_;

    if (tid == 0) *nresp = 0;
    for (int i = tid; i < S_; i += 512) {
      gl[i] = D_emb[d_seq[b * S_ + i]];
      rl[i] = r_seq[b * S_ + i];
      jl[i] = c2_seq[b * S_ + i];
      done[i] = 0;
    }
    if (tid < DV_) {
      const int d = tid;
      const float4* w3r = reinterpret_cast<const float4*>(W3 + (size_t)d * 3 * DV_);
      const float4* vc4 = reinterpret_cast<const float4*>(v_c2);
      const float4* vd4 = reinterpret_cast<const float4*>(v_d);
      const float4* re4 = reinterpret_cast<const float4*>(R_emb);
      float a3 = 0, u3 = 0, q0 = 0, q1 = 0;
#pragma unroll 8
      for (int k = 0; k < DV_ / 4; ++k) {
        float4 a = w3r[k], cc = vc4[k];
        a3 += a.x * cc.x + a.y * cc.y + a.z * cc.z + a.w * cc.w;
        float4 u = w3r[DV_ / 4 + k], dd = vd4[k];
        u3 += u.x * dd.x + u.y * dd.y + u.z * dd.z + u.w * dd.w;
        float4 cq = w3r[2 * (DV_ / 4) + k];
        float4 r0 = re4[k], r1 = re4[DV_ / 4 + k];
        q0 += cq.x * r0.x + cq.y * r0.y + cq.z * r0.z + cq.w * r0.w;
        q1 += cq.x * r1.x + cq.y * r1.y + cq.z * r1.z + cq.w * r1.w;
      }
      const float bb = b3[d];
      a3s[d] = a3; u3s[d] = u3; q0s[d] = q0 + bb; q1s[d] = q1 + bb;
      w4s[d] = W4[d];
    }
    __syncthreads();
    if (tid < S_) {
      const int jj = jl[tid];
      int p = -1;
      for (int q = tid - 1; q >= 0; --q)
        if (jl[q] == jj) { p = q; break; }
      prevs[tid] = p;
    }
    const float b4v = b4[0];
    __syncthreads();

    // thread-per-event wavefront resolution (R14-validated)
    const int t = tid;
    const float gv = (t < S_) ? gl[t] : 0.f;
    const int rv = (t < S_) ? rl[t] : 0;
    const int p = (t < S_) ? prevs[t] : -1;
    bool mine_done = (t >= S_);

    for (int round = 0; round < S_; ++round) {
      float myval = 0.f;
      bool computed = false;
      if (!mine_done && (p < 0 || done[p])) {
        const float beta = (p < 0) ? 0.f : vals[p];
        const float4* a34 = reinterpret_cast<const float4*>(a3s);
        const float4* u34 = reinterpret_cast<const float4*>(u3s);
        const float4* q04 = reinterpret_cast<const float4*>(q0s);
        const float4* q14 = reinterpret_cast<const float4*>(q1s);
        const float4* w44 = reinterpret_cast<const float4*>(w4s);
        float acc = 0.f;
#pragma unroll 8
        for (int k = 0; k < DV_ / 4; ++k) {
          float4 a = a34[k], u = u34[k];
          float4 q = rv ? q14[k] : q04[k];
          float4 ww = w44[k];
          float h0 = beta * a.x + gv * u.x + q.x;
          float h1 = beta * a.y + gv * u.y + q.y;
          float h2 = beta * a.z + gv * u.z + q.z;
          float h3 = beta * a.w + gv * u.w + q.w;
          acc += ww.x * fmaxf(h0, 0.f) + ww.y * fmaxf(h1, 0.f) +
                 ww.z * fmaxf(h2, 0.f) + ww.w * fmaxf(h3, 0.f);
        }
        myval = acc + b4v;
        computed = true;
      }
      __syncthreads();
      if (computed) {
        vals[t] = myval;
        done[t] = 1;
        mine_done = true;
        atomicAdd(nresp, 1);
      }
      __syncthreads();
      if (*nresp >= S_) break;
    }
    __syncthreads();

    // ---------- streaming fill: rows [s0, s0+100) ----------
    f4v v0 = {0.f, 0.f, 0.f, 0.f}, v1 = v0;

#define APPLY_EVT(T)                                                          \
    {                                                                         \
      const int j_ = jl[(T)];                                                 \
      const int f_ = j_ >> 2;                                                 \
      if ((f_ & 511) == tid) {                                                \
        const float vv_ = vals[(T)];                                          \
        const int rr_ = f_ >> 9, q_ = j_ & 3;                                 \
        if (rr_ == 0) {                                                       \
          if (q_ == 0) v0.x = vv_; else if (q_ == 1) v0.y = vv_;              \
          else if (q_ == 2) v0.z = vv_; else v0.w = vv_;                      \
        } else {                                                              \
          if (q_ == 0) v1.x = vv_; else if (q_ == 1) v1.y = vv_;              \
          else if (q_ == 2) v1.z = vv_; else v1.w = vv_;                      \
        }                                                                     \
      }                                                                       \
    }

    for (int tt = 0; tt < s0; ++tt) APPLY_EVT(tt);

    f4v* dst4 = reinterpret_cast<f4v*>(out_c2 + (size_t)b * S_ * NC2_);
    for (int s = s0; s < s0 + 100; ++s) {
      APPLY_EVT(s);
      f4v* drow = dst4 + (size_t)s * (NC2_ / 4);
      __builtin_nontemporal_store(v0, drow + tid);
      __builtin_nontemporal_store(v1, drow + tid + 512);
    }
#undef APPLY_EVT
  }
}

extern "C" void kernel_launch(void* const* d_in, const int* in_sizes, int n_in,
                              void* d_out, int out_size, void* d_ws, size_t ws_size,
                              hipStream_t stream) {
  const int* c2_seq = (const int*)d_in[1];
  const int* d_seq = (const int*)d_in[3];
  const int* r_seq = (const int*)d_in[4];
  const float* D_emb = (const float*)d_in[5];
  const float* v_d = (const float*)d_in[6];
  const float* v_c2 = (const float*)d_in[7];
  const float* R_emb = (const float*)d_in[8];
  const float* W_ih = (const float*)d_in[9];
  const float* W_hh = (const float*)d_in[10];
  const float* b_ih = (const float*)d_in[11];
  const float* b_hh = (const float*)d_in[12];
  const float* W1 = (const float*)d_in[13];
  const float* b1 = (const float*)d_in[14];
  const float* W2 = (const float*)d_in[15];
  const float* b2 = (const float*)d_in[16];
  const float* W3 = (const float*)d_in[17];
  const float* b3 = (const float*)d_in[18];
  const float* W4 = (const float*)d_in[19];
  const float* b4 = (const float*)d_in[20];

  float* out = (float*)d_out;
  float* out_alpha = out;                                  // [B,S]
  float* out_h = out + B_ * S_;                            // [B,S,DV]
  float* out_c2 = out + B_ * S_ + (size_t)B_ * S_ * DV_;   // [B,S,NC2]

  k1_main<<<dim3(B_ + 2 * B_), dim3(512), 0, stream>>>(
      c2_seq, d_seq, r_seq, D_emb, v_d, v_c2, R_emb, W_ih, W_hh, b_ih, b_hh,
      W1, b1, W2, b2, W3, b3, W4, b4, out_alpha, out_h, out_c2);
}

// Round 22
// 134.153 us; speedup vs baseline: 1.0572x; 1.0572x over previous
//
#include <hip/hip_runtime.h>

namespace {
constexpr int B_ = 64, S_ = 200, DV_ = 128, NC2_ = 4096;
}

typedef float f4v __attribute__((ext_vector_type(4)));
typedef float f32x4 __attribute__((ext_vector_type(4)));
typedef _Float16 half8 __attribute__((ext_vector_type(8)));

// LDS-only barrier: no vmcnt drain.
__device__ __forceinline__ void lds_sync() {
  asm volatile("s_waitcnt lgkmcnt(0)\n\ts_barrier" ::: "memory");
}

// ---------------------------------------------------------------------------
// K1: blocks [0,64):   GRU per batch (broadcast-MFMA loop) + swizzled f16
//                      history append + MFMA alpha tail (no spill).
//     blocks [64,128): per-batch {parallel scan -> streaming fill}.
// ---------------------------------------------------------------------------
__global__ __launch_bounds__(512, 1) void k1_main(
    const int* __restrict__ c2_seq, const int* __restrict__ d_seq,
    const int* __restrict__ r_seq, const float* __restrict__ D_emb,
    const float* __restrict__ v_d, const float* __restrict__ v_c2,
    const float* __restrict__ R_emb,
    const float* __restrict__ W_ih, const float* __restrict__ W_hh,
    const float* __restrict__ b_ih, const float* __restrict__ b_hh,
    const float* __restrict__ W1, const float* __restrict__ b1,
    const float* __restrict__ W2, const float* __restrict__ b2,
    const float* __restrict__ W3, const float* __restrict__ b3,
    const float* __restrict__ W4, const float* __restrict__ b4,
    float* __restrict__ out_alpha, float* __restrict__ out_h,
    float* __restrict__ out_c2)
{
  __shared__ __align__(16) char smem[18944 + 208 * DV_ * 2];
  const int tid = threadIdx.x;

  if (blockIdx.x < B_) {
    // ------------------ GRU for batch b ------------------
    const int b = blockIdx.x;
    _Float16* hist = reinterpret_cast<_Float16*>(smem);          // [2][128] f16
    float* gl = reinterpret_cast<float*>(smem + 512);            // [200]
    int* rl = reinterpret_cast<int*>(smem + 1312);               // [200]
    float* u_l = reinterpret_cast<float*>(smem + 2112);          // [384] x4
    float* p0_l = u_l + 384;
    float* p1_l = p0_l + 384;
    float* bh_l = p1_l + 384;
    _Float16* fullh = reinterpret_cast<_Float16*>(smem + 18944); // [208][128]

    for (int i = tid; i < S_; i += 512) {
      gl[i] = D_emb[d_seq[b * S_ + i]];
      rl[i] = r_seq[b * S_ + i];
    }
    if (tid < 256) reinterpret_cast<_Float16*>(hist)[tid] = (_Float16)0.f;
    // zero fullh rows 200..207 (tail tile padding)
    {
      uint* fz = reinterpret_cast<uint*>(fullh + 200 * DV_);
      for (int i = tid; i < 8 * DV_ / 2; i += 512) fz[i] = 0u;
    }

    // collapsed input projections per gate row -> LDS
    if (tid < 384) {
      const int row = tid;
      const float4* wi =
          reinterpret_cast<const float4*>(W_ih + (size_t)row * 2 * DV_);
      const float4* vd4 = reinterpret_cast<const float4*>(v_d);
      const float4* re4 = reinterpret_cast<const float4*>(R_emb);
      float uu = 0.f, pp0 = 0.f, pp1 = 0.f;
#pragma unroll 8
      for (int k = 0; k < DV_ / 4; ++k) {
        float4 a = wi[k], vv = vd4[k];
        uu += a.x * vv.x + a.y * vv.y + a.z * vv.z + a.w * vv.w;
        float4 c = wi[DV_ / 4 + k];
        float4 r0 = re4[k], r1 = re4[DV_ / 4 + k];
        pp0 += c.x * r0.x + c.y * r0.y + c.z * r0.z + c.w * r0.w;
        pp1 += c.x * r1.x + c.y * r1.y + c.z * r1.z + c.w * r1.w;
      }
      const float bi = b_ih[row];
      u_l[row] = uu; p0_l[row] = pp0 + bi; p1_l[row] = pp1 + bi;
      bh_l[row] = b_hh[row];
    }

    // B-fragments (W_hh^T): lane l holds B[k=(l>>4)*8+j][col=l&15].
    const int w = tid >> 6, l = tid & 63;
    const int col = l & 15, kg = l >> 4;
    const int d = 16 * w + col;
    half8 bf[3][4];
#pragma unroll
    for (int g = 0; g < 3; ++g) {
      const float* wr = W_hh + (size_t)(g * DV_ + d) * DV_;
#pragma unroll
      for (int kt = 0; kt < 4; ++kt) {
        const int k0 = kt * 32 + kg * 8;
        const float4 lo = *reinterpret_cast<const float4*>(wr + k0);
        const float4 hi = *reinterpret_cast<const float4*>(wr + k0 + 4);
        half8 hb;
        hb[0] = (_Float16)lo.x; hb[1] = (_Float16)lo.y;
        hb[2] = (_Float16)lo.z; hb[3] = (_Float16)lo.w;
        hb[4] = (_Float16)hi.x; hb[5] = (_Float16)hi.y;
        hb[6] = (_Float16)hi.z; hb[7] = (_Float16)hi.w;
        bf[g][kt] = hb;
      }
    }
    __syncthreads();

    float u3[3], p03[3], p13[3], bh3[3];
#pragma unroll
    for (int g = 0; g < 3; ++g) {
      u3[g] = u_l[g * DV_ + d];
      p03[g] = p0_l[g * DV_ + d];
      p13[g] = p1_l[g * DV_ + d];
      bh3[g] = bh_l[g * DV_ + d];
    }
    float hprev = 0.f;
    float gv = gl[0];
    int rv = rl[0];

    float* outp = out_h + (size_t)b * S_ * DV_ + d;
    for (int t = 0; t < S_; ++t) {
      const int cur = t & 1;
      half8 af[4];
#pragma unroll
      for (int kt = 0; kt < 4; ++kt)
        af[kt] = *reinterpret_cast<const half8*>(&hist[cur * DV_ + kt * 32 + kg * 8]);
      f32x4 a0 = {0.f, 0.f, 0.f, 0.f}, a1 = a0, a2 = a0;
#pragma unroll
      for (int kt = 0; kt < 4; ++kt) {
        a0 = __builtin_amdgcn_mfma_f32_16x16x32_f16(af[kt], bf[0][kt], a0, 0, 0, 0);
        a1 = __builtin_amdgcn_mfma_f32_16x16x32_f16(af[kt], bf[1][kt], a1, 0, 0, 0);
        a2 = __builtin_amdgcn_mfma_f32_16x16x32_f16(af[kt], bf[2][kt], a2, 0, 0, 0);
      }
      const float xr = gv * u3[0] + (rv ? p13[0] : p03[0]);
      const float xz = gv * u3[1] + (rv ? p13[1] : p03[1]);
      const float xn = gv * u3[2] + (rv ? p13[2] : p03[2]);
      const float r = 1.f / (1.f + __expf(-(xr + a0[0] + bh3[0])));
      const float z = 1.f / (1.f + __expf(-(xz + a1[0] + bh3[1])));
      const float nx = xn + r * (a2[0] + bh3[2]);
      const float e2 = __expf(2.f * nx);
      const float n = (e2 - 1.f) / (e2 + 1.f);
      const float hnew = (1.f - z) * n + z * hprev;
      hprev = hnew;
      if (kg == 0) {
        outp[(size_t)t * DV_] = hnew;                 // fire-and-forget f32
        const _Float16 hf = (_Float16)hnew;
        hist[(cur ^ 1) * DV_ + d] = hf;
        fullh[t * DV_ + (d ^ ((t & 7) << 3))] = hf;   // swizzled history
      }
      if (t + 1 < S_) { gv = gl[t + 1]; rv = rl[t + 1]; }
      lds_sync();
    }

    // ---------- MFMA alpha tail: y = fullh @ W1^T, 13 s-tiles ----------
    half8 bf1[4];
    {
      const float* wr1 = W1 + (size_t)d * DV_;
#pragma unroll
      for (int kt = 0; kt < 4; ++kt) {
        const int k0 = kt * 32 + kg * 8;
        const float4 lo = *reinterpret_cast<const float4*>(wr1 + k0);
        const float4 hi = *reinterpret_cast<const float4*>(wr1 + k0 + 4);
        half8 hb;
        hb[0] = (_Float16)lo.x; hb[1] = (_Float16)lo.y;
        hb[2] = (_Float16)lo.z; hb[3] = (_Float16)lo.w;
        hb[4] = (_Float16)hi.x; hb[5] = (_Float16)hi.y;
        hb[6] = (_Float16)hi.z; hb[7] = (_Float16)hi.w;
        bf1[kt] = hb;
      }
    }
    const float b1v = b1[d], w2v = W2[d], b2v = b2[0];
    float* alphaAcc = u_l;  // reuse dead LDS (384 floats >= 208)
    if (tid < 208) alphaAcc[tid] = b2v;
    lds_sync();
    for (int st = 0; st < 13; ++st) {
      const int row = 16 * st + col;   // A row = lane&15
      half8 af2[4];
#pragma unroll
      for (int kt = 0; kt < 4; ++kt) {
        const int c0 = (kt * 32 + kg * 8) ^ ((row & 7) << 3);
        af2[kt] = *reinterpret_cast<const half8*>(&fullh[row * DV_ + c0]);
      }
      f32x4 y = {0.f, 0.f, 0.f, 0.f};
#pragma unroll
      for (int kt = 0; kt < 4; ++kt)
        y = __builtin_amdgcn_mfma_f32_16x16x32_f16(af2[kt], bf1[kt], y, 0, 0, 0);
#pragma unroll
      for (int j = 0; j < 4; ++j) {
        float part = w2v * fmaxf(y[j] + b1v, 0.f);
        part += __shfl_xor(part, 1);
        part += __shfl_xor(part, 2);
        part += __shfl_xor(part, 4);
        part += __shfl_xor(part, 8);
        if (col == 0) atomicAdd(&alphaAcc[16 * st + 4 * kg + j], part);
      }
    }
    lds_sync();
    if (tid < S_) out_alpha[b * S_ + tid] = alphaAcc[tid];
  } else {
    // ------------- per-batch parallel scan + streaming fill -------------
    const int b = blockIdx.x - B_;
    float* a3s = reinterpret_cast<float*>(smem);            // [128] x5
    float* u3s = a3s + DV_;
    float* q0s = u3s + DV_;
    float* q1s = q0s + DV_;
    float* w4s = q1s + DV_;
    float* vals = w4s + DV_;                                // [200]
    float* gl = vals + S_;                                  // [200]
    int* rl = reinterpret_cast<int*>(gl + S_);
    int* jl = rl + S_;
    int* prevs = jl + S_;
    int* done = prevs + S_;
    int* nresp = done + S_;

    if (tid == 0) *nresp = 0;
    for (int i = tid; i < S_; i += 512) {
      gl[i] = D_emb[d_seq[b * S_ + i]];
      rl[i] = r_seq[b * S_ + i];
      jl[i] = c2_seq[b * S_ + i];
      done[i] = 0;
    }
    if (tid < DV_) {
      const int d = tid;
      const float4* w3r = reinterpret_cast<const float4*>(W3 + (size_t)d * 3 * DV_);
      const float4* vc4 = reinterpret_cast<const float4*>(v_c2);
      const float4* vd4 = reinterpret_cast<const float4*>(v_d);
      const float4* re4 = reinterpret_cast<const float4*>(R_emb);
      float a3 = 0, u3 = 0, q0 = 0, q1 = 0;
#pragma unroll 8
      for (int k = 0; k < DV_ / 4; ++k) {
        float4 a = w3r[k], cc = vc4[k];
        a3 += a.x * cc.x + a.y * cc.y + a.z * cc.z + a.w * cc.w;
        float4 u = w3r[DV_ / 4 + k], dd = vd4[k];
        u3 += u.x * dd.x + u.y * dd.y + u.z * dd.z + u.w * dd.w;
        float4 cq = w3r[2 * (DV_ / 4) + k];
        float4 r0 = re4[k], r1 = re4[DV_ / 4 + k];
        q0 += cq.x * r0.x + cq.y * r0.y + cq.z * r0.z + cq.w * r0.w;
        q1 += cq.x * r1.x + cq.y * r1.y + cq.z * r1.z + cq.w * r1.w;
      }
      const float bb = b3[d];
      a3s[d] = a3; u3s[d] = u3; q0s[d] = q0 + bb; q1s[d] = q1 + bb;
      w4s[d] = W4[d];
    }
    __syncthreads();
    if (tid < S_) {
      const int jj = jl[tid];
      int p = -1;
      for (int q = tid - 1; q >= 0; --q)
        if (jl[q] == jj) { p = q; break; }
      prevs[tid] = p;
    }
    const float b4v = b4[0];
    __syncthreads();

    // thread-per-event wavefront resolution (R14-validated)
    const int t = tid;
    const float gv = (t < S_) ? gl[t] : 0.f;
    const int rv = (t < S_) ? rl[t] : 0;
    const int p = (t < S_) ? prevs[t] : -1;
    bool mine_done = (t >= S_);

    for (int round = 0; round < S_; ++round) {
      float myval = 0.f;
      bool computed = false;
      if (!mine_done && (p < 0 || done[p])) {
        const float beta = (p < 0) ? 0.f : vals[p];
        const float4* a34 = reinterpret_cast<const float4*>(a3s);
        const float4* u34 = reinterpret_cast<const float4*>(u3s);
        const float4* q04 = reinterpret_cast<const float4*>(q0s);
        const float4* q14 = reinterpret_cast<const float4*>(q1s);
        const float4* w44 = reinterpret_cast<const float4*>(w4s);
        float acc = 0.f;
#pragma unroll 8
        for (int k = 0; k < DV_ / 4; ++k) {
          float4 a = a34[k], u = u34[k];
          float4 q = rv ? q14[k] : q04[k];
          float4 ww = w44[k];
          float h0 = beta * a.x + gv * u.x + q.x;
          float h1 = beta * a.y + gv * u.y + q.y;
          float h2 = beta * a.z + gv * u.z + q.z;
          float h3 = beta * a.w + gv * u.w + q.w;
          acc += ww.x * fmaxf(h0, 0.f) + ww.y * fmaxf(h1, 0.f) +
                 ww.z * fmaxf(h2, 0.f) + ww.w * fmaxf(h3, 0.f);
        }
        myval = acc + b4v;
        computed = true;
      }
      __syncthreads();
      if (computed) {
        vals[t] = myval;
        done[t] = 1;
        mine_done = true;
        atomicAdd(nresp, 1);
      }
      __syncthreads();
      if (*nresp >= S_) break;
    }
    __syncthreads();

    // ---------- streaming fill: all 200 rows from this one block ----------
    f4v v0 = {0.f, 0.f, 0.f, 0.f}, v1 = v0;
    f4v* dst4 = reinterpret_cast<f4v*>(out_c2 + (size_t)b * S_ * NC2_);
    for (int s = 0; s < S_; ++s) {
      const int j_ = jl[s];
      const int f_ = j_ >> 2;
      if ((f_ & 511) == tid) {
        const float vv_ = vals[s];
        const int rr_ = f_ >> 9, q_ = j_ & 3;
        if (rr_ == 0) {
          if (q_ == 0) v0.x = vv_; else if (q_ == 1) v0.y = vv_;
          else if (q_ == 2) v0.z = vv_; else v0.w = vv_;
        } else {
          if (q_ == 0) v1.x = vv_; else if (q_ == 1) v1.y = vv_;
          else if (q_ == 2) v1.z = vv_; else v1.w = vv_;
        }
      }
      f4v* drow = dst4 + (size_t)s * (NC2_ / 4);
      __builtin_nontemporal_store(v0, drow + tid);
      __builtin_nontemporal_store(v1, drow + tid + 512);
    }
  }
}

extern "C" void kernel_launch(void* const* d_in, const int* in_sizes, int n_in,
                              void* d_out, int out_size, void* d_ws, size_t ws_size,
                              hipStream_t stream) {
  const int* c2_seq = (const int*)d_in[1];
  const int* d_seq = (const int*)d_in[3];
  const int* r_seq = (const int*)d_in[4];
  const float* D_emb = (const float*)d_in[5];
  const float* v_d = (const float*)d_in[6];
  const float* v_c2 = (const float*)d_in[7];
  const float* R_emb = (const float*)d_in[8];
  const float* W_ih = (const float*)d_in[9];
  const float* W_hh = (const float*)d_in[10];
  const float* b_ih = (const float*)d_in[11];
  const float* b_hh = (const float*)d_in[12];
  const float* W1 = (const float*)d_in[13];
  const float* b1 = (const float*)d_in[14];
  const float* W2 = (const float*)d_in[15];
  const float* b2 = (const float*)d_in[16];
  const float* W3 = (const float*)d_in[17];
  const float* b3 = (const float*)d_in[18];
  const float* W4 = (const float*)d_in[19];
  const float* b4 = (const float*)d_in[20];

  float* out = (float*)d_out;
  float* out_alpha = out;                                  // [B,S]
  float* out_h = out + B_ * S_;                            // [B,S,DV]
  float* out_c2 = out + B_ * S_ + (size_t)B_ * S_ * DV_;   // [B,S,NC2]

  k1_main<<<dim3(2 * B_), dim3(512), 0, stream>>>(
      c2_seq, d_seq, r_seq, D_emb, v_d, v_c2, R_emb, W_ih, W_hh, b_ih, b_hh,
      W1, b1, W2, b2, W3, b3, W4, b4, out_alpha, out_h, out_c2);
}